// Round 1
// baseline (789.352 us; speedup 1.0000x reference)
//
#include <hip/hip_runtime.h>
#include <hip/hip_bf16.h>

typedef __bf16 bf16x8 __attribute__((ext_vector_type(8)));
typedef float f32x4 __attribute__((ext_vector_type(4)));
using bf16 = __hip_bfloat16;

#define MFMA16(a, b, c) __builtin_amdgcn_mfma_f32_16x16x32_bf16((a), (b), (c), 0, 0, 0)

constexpr int Cdim = 512;   // channels
constexpr int Nsp  = 4096;  // d*h*w
constexpr int NB   = 2;     // batch

// ---------------------------------------------------------------- weights fp32 -> bf16
__global__ __launch_bounds__(256) void k_cvt_w(const float* __restrict__ w, bf16* __restrict__ o) {
    int i = blockIdx.x * 256 + threadIdx.x;  // grid exactly covers 512*512
    o[i] = __float2bfloat16(w[i]);
}

// ---------------------------------------------------------------- groupnorm stats
// one block per (b,g); group data is a contiguous 16*4096 float slab
__global__ __launch_bounds__(256) void k_gn_stats(const float* __restrict__ x, float* __restrict__ stats) {
    int bg = blockIdx.x;  // 0..63
    const float4* p = (const float4*)(x + (size_t)bg * (16 * 4096));
    float s = 0.f, s2 = 0.f;
    for (int i = threadIdx.x; i < 16384; i += 256) {
        float4 v = p[i];
        s  += v.x + v.y + v.z + v.w;
        s2 += v.x * v.x + v.y * v.y + v.z * v.z + v.w * v.w;
    }
    #pragma unroll
    for (int off = 32; off; off >>= 1) { s += __shfl_xor(s, off); s2 += __shfl_xor(s2, off); }
    __shared__ float rs[4], rs2[4];
    int w = threadIdx.x >> 6;
    if ((threadIdx.x & 63) == 0) { rs[w] = s; rs2[w] = s2; }
    __syncthreads();
    if (threadIdx.x == 0) {
        float S = rs[0] + rs[1] + rs[2] + rs[3];
        float S2 = rs2[0] + rs2[1] + rs2[2] + rs2[3];
        float mean = S * (1.f / 65536.f);
        float var  = S2 * (1.f / 65536.f) - mean * mean;
        stats[bg * 2]     = mean;
        stats[bg * 2 + 1] = rsqrtf(var + 1e-6f);
    }
}

// ---------------------------------------------------------------- groupnorm apply + transpose -> ht[b,n,c] bf16
__global__ __launch_bounds__(256) void k_gn_apply(const float* __restrict__ x, const float* __restrict__ stats,
                                                  const float* __restrict__ gamma, const float* __restrict__ beta,
                                                  bf16* __restrict__ ht) {
    int b = blockIdx.y;
    int n0 = blockIdx.x * 64;
    int tid = threadIdx.x;
    __shared__ float tile[64][65];
    int nn_l = tid & 63, cc0 = tid >> 6;  // load mapping (coalesced along n)
    int cc_w = tid & 63, nn0 = tid >> 6;  // write mapping (coalesced along c)
    for (int c0 = 0; c0 < Cdim; c0 += 64) {
        #pragma unroll
        for (int p = 0; p < 16; ++p) {
            int cc = p * 4 + cc0;
            tile[cc][nn_l] = x[(size_t)(b * Cdim + c0 + cc) * Nsp + n0 + nn_l];
        }
        __syncthreads();
        int c = c0 + cc_w, g = c >> 4;
        float mean = stats[(b * 32 + g) * 2];
        float rstd = stats[(b * 32 + g) * 2 + 1];
        float ga = gamma[c], be = beta[c];
        #pragma unroll
        for (int p = 0; p < 16; ++p) {
            int nn = p * 4 + nn0;
            float v = tile[cc_w][nn];
            ht[(size_t)(b * Nsp + n0 + nn) * Cdim + c] = __float2bfloat16((v - mean) * rstd * ga + be);
        }
        __syncthreads();
    }
}

// ---------------------------------------------------------------- NT GEMM: out[m][n] = sum_k A[m][k]*B[n][k] (+bias)(+resid)
// K = 512 fixed. 128x128 block tile, BK=64, 4 waves in 2x2, each wave 64x64 (4x4 mfma tiles).
template <int OUT_F32, int BIAS_M, int RESID>
__global__ __launch_bounds__(256) void k_gemm_nt(
    const bf16* __restrict__ A, long long As,
    const bf16* __restrict__ B, long long Bs,
    const float* __restrict__ bias,
    const float* __restrict__ resid, long long Rs,
    void* __restrict__ outv, long long Os,
    int N) {
    constexpr int K = 512;
    const int bm = blockIdx.x, bn = blockIdx.y, bt = blockIdx.z;
    const bf16* Ab = A + (size_t)bt * As;
    const bf16* Bb = B + (size_t)bt * Bs;
    const int tid = threadIdx.x, lane = tid & 63, w = tid >> 6;
    const int quad = lane >> 4, l16 = lane & 15;
    const int wm = w >> 1, wn = w & 1;
    __shared__ __align__(16) bf16 Asub[128][72];  // pitch 72 elems (144B): b128 reads land ~2-way
    __shared__ __align__(16) bf16 Bsub[128][72];
    f32x4 zero4 = {0.f, 0.f, 0.f, 0.f};
    f32x4 acc[4][4];
    #pragma unroll
    for (int i = 0; i < 4; ++i)
        #pragma unroll
        for (int j = 0; j < 4; ++j) acc[i][j] = zero4;
    const int row0 = bm * 128, col0 = bn * 128;
    const int srow = tid >> 3, skc = (tid & 7) * 8;
    for (int k0 = 0; k0 < K; k0 += 64) {
        #pragma unroll
        for (int it = 0; it < 4; ++it) {
            int r = it * 32 + srow;
            *(uint4*)&Asub[r][skc] = *(const uint4*)&Ab[(size_t)(row0 + r) * K + k0 + skc];
            *(uint4*)&Bsub[r][skc] = *(const uint4*)&Bb[(size_t)(col0 + r) * K + k0 + skc];
        }
        __syncthreads();
        #pragma unroll
        for (int ks = 0; ks < 2; ++ks) {
            bf16x8 af[4], bfr[4];
            #pragma unroll
            for (int t = 0; t < 4; ++t) af[t] = *(const bf16x8*)&Asub[wm * 64 + t * 16 + l16][ks * 32 + quad * 8];
            #pragma unroll
            for (int t = 0; t < 4; ++t) bfr[t] = *(const bf16x8*)&Bsub[wn * 64 + t * 16 + l16][ks * 32 + quad * 8];
            #pragma unroll
            for (int tm = 0; tm < 4; ++tm)
                #pragma unroll
                for (int tn = 0; tn < 4; ++tn) acc[tm][tn] = MFMA16(af[tm], bfr[tn], acc[tm][tn]);
        }
        __syncthreads();
    }
    #pragma unroll
    for (int tm = 0; tm < 4; ++tm)
        #pragma unroll
        for (int tn = 0; tn < 4; ++tn)
            #pragma unroll
            for (int r = 0; r < 4; ++r) {
                int row = row0 + wm * 64 + tm * 16 + quad * 4 + r;
                int col = col0 + wn * 64 + tn * 16 + l16;
                float v = acc[tm][tn][r];
                v += BIAS_M ? bias[row] : bias[col];
                if (RESID) v += resid[(size_t)bt * Rs + (size_t)row * N + col];
                size_t oidx = (size_t)bt * Os + (size_t)row * N + col;
                if (OUT_F32) ((float*)outv)[oidx] = v;
                else         ((bf16*)outv)[oidx] = __float2bfloat16(v);
            }
}

// ---------------------------------------------------------------- flash attention
// Qt,Kt: [b, n, c] bf16.  V: [b, c, n] bf16.  Ot: [b, n, c] bf16 (pre-normalized by l inside).
// Br=32, Bc=64, 256 threads. Wave (wr,wc): QK^T rows wr*16..+16, cols wc*32..+32;
// PV rows wr*16..+16, O cols wc*256..+256. Q frags pinned in registers.
__global__ __launch_bounds__(256, 1) void k_flash(const bf16* __restrict__ Qt, const bf16* __restrict__ Kt,
                                                  const bf16* __restrict__ V, bf16* __restrict__ Ot) {
    const int b = blockIdx.y;
    const int i0 = blockIdx.x * 32;
    const int tid = threadIdx.x, lane = tid & 63, w = tid >> 6;
    const int quad = lane >> 4, l16 = lane & 15;
    const int wr = w >> 1, wc = w & 1;
    constexpr float SCALE = 0.04419417382415922f;  // 512^-0.5

    __shared__ __align__(16) float S_lds[32][68];
    __shared__ __align__(16) bf16 P_lds[32][72];
    __shared__ float m_s[32], l_s[32], alpha_s[32];

    // Q fragments: rows i0 + wr*16 + l16, k = s*32 + quad*8 + (0..7)
    bf16x8 qf[16];
    {
        const bf16* qrow = Qt + (size_t)(b * Nsp + i0 + wr * 16 + l16) * Cdim + quad * 8;
        #pragma unroll
        for (int s = 0; s < 16; ++s) qf[s] = *(const bf16x8*)(qrow + s * 32);
    }
    f32x4 zero4 = {0.f, 0.f, 0.f, 0.f};
    f32x4 o_acc[16];
    #pragma unroll
    for (int t = 0; t < 16; ++t) o_acc[t] = zero4;

    if (tid < 32) { m_s[tid] = -1e30f; l_s[tid] = 0.f; }
    __syncthreads();

    const int srow = tid >> 3;  // softmax: 8 threads per row
    const int sub = tid & 7;

    for (int j0 = 0; j0 < Nsp; j0 += 64) {
        // ---- S = (Q K^T) * scale ----
        f32x4 s_acc0 = zero4, s_acc1 = zero4;
        const bf16* krow0 = Kt + (size_t)(b * Nsp + j0 + wc * 32 + l16) * Cdim + quad * 8;
        const bf16* krow1 = krow0 + 16 * Cdim;
        #pragma unroll
        for (int s = 0; s < 16; ++s) {
            bf16x8 kf0 = *(const bf16x8*)(krow0 + s * 32);
            bf16x8 kf1 = *(const bf16x8*)(krow1 + s * 32);
            s_acc0 = MFMA16(qf[s], kf0, s_acc0);
            s_acc1 = MFMA16(qf[s], kf1, s_acc1);
        }
        #pragma unroll
        for (int r = 0; r < 4; ++r) {
            S_lds[wr * 16 + quad * 4 + r][wc * 32 + l16]      = s_acc0[r] * SCALE;
            S_lds[wr * 16 + quad * 4 + r][wc * 32 + 16 + l16] = s_acc1[r] * SCALE;
        }
        __syncthreads();
        // ---- online softmax (8 threads per row; all within one wave per row) ----
        {
            float sv[8];
            float mloc = -1e30f;
            #pragma unroll
            for (int e = 0; e < 8; ++e) { sv[e] = S_lds[srow][sub * 8 + e]; mloc = fmaxf(mloc, sv[e]); }
            #pragma unroll
            for (int off = 1; off < 8; off <<= 1) mloc = fmaxf(mloc, __shfl_xor(mloc, off));
            float m_old = m_s[srow];
            float m_new = fmaxf(m_old, mloc);
            float psum = 0.f;
            #pragma unroll
            for (int e = 0; e < 8; ++e) {
                float pe = __expf(sv[e] - m_new);
                psum += pe;
                P_lds[srow][sub * 8 + e] = __float2bfloat16(pe);
            }
            #pragma unroll
            for (int off = 1; off < 8; off <<= 1) psum += __shfl_xor(psum, off);
            if (sub == 0) {
                float alpha = __expf(m_old - m_new);
                m_s[srow] = m_new;
                l_s[srow] = l_s[srow] * alpha + psum;
                alpha_s[srow] = alpha;
            }
        }
        __syncthreads();
        // ---- rescale O, then O += P V^T ----
        float al[4];
        #pragma unroll
        for (int r = 0; r < 4; ++r) al[r] = alpha_s[wr * 16 + quad * 4 + r];
        #pragma unroll
        for (int t = 0; t < 16; ++t) {
            o_acc[t][0] *= al[0]; o_acc[t][1] *= al[1];
            o_acc[t][2] *= al[2]; o_acc[t][3] *= al[3];
        }
        bf16x8 a0 = *(const bf16x8*)&P_lds[wr * 16 + l16][quad * 8];
        bf16x8 a1 = *(const bf16x8*)&P_lds[wr * 16 + l16][32 + quad * 8];
        const bf16* vbase = V + (size_t)(b * Cdim + wc * 256 + l16) * Nsp + j0 + quad * 8;
        #pragma unroll
        for (int t = 0; t < 16; ++t) {
            bf16x8 v0 = *(const bf16x8*)(vbase + (size_t)t * 16 * Nsp);
            bf16x8 v1 = *(const bf16x8*)(vbase + (size_t)t * 16 * Nsp + 32);
            o_acc[t] = MFMA16(a0, v0, o_acc[t]);
            o_acc[t] = MFMA16(a1, v1, o_acc[t]);
        }
        __syncthreads();
    }
    float li[4];
    #pragma unroll
    for (int r = 0; r < 4; ++r) li[r] = 1.f / l_s[wr * 16 + quad * 4 + r];
    #pragma unroll
    for (int t = 0; t < 16; ++t)
        #pragma unroll
        for (int r = 0; r < 4; ++r)
            Ot[(size_t)(b * Nsp + i0 + wr * 16 + quad * 4 + r) * Cdim + wc * 256 + t * 16 + l16] =
                __float2bfloat16(o_acc[t][r] * li[r]);
}

// ---------------------------------------------------------------- launcher
extern "C" void kernel_launch(void* const* d_in, const int* in_sizes, int n_in,
                              void* d_out, int out_size, void* d_ws, size_t ws_size,
                              hipStream_t stream) {
    const float* x     = (const float*)d_in[0];
    const float* gamma = (const float*)d_in[1];
    const float* beta  = (const float*)d_in[2];
    const float* wq = (const float*)d_in[3];  const float* bq = (const float*)d_in[4];
    const float* wk = (const float*)d_in[5];  const float* bk = (const float*)d_in[6];
    const float* wv = (const float*)d_in[7];  const float* bv = (const float*)d_in[8];
    const float* wo = (const float*)d_in[9];  const float* bo = (const float*)d_in[10];
    float* out = (float*)d_out;

    char* ws = (char*)d_ws;
    float* stats = (float*)ws;
    size_t off = 1024;
    bf16* wqb = (bf16*)(ws + off); off += (size_t)Cdim * Cdim * 2;
    bf16* wkb = (bf16*)(ws + off); off += (size_t)Cdim * Cdim * 2;
    bf16* wvb = (bf16*)(ws + off); off += (size_t)Cdim * Cdim * 2;
    bf16* wob = (bf16*)(ws + off); off += (size_t)Cdim * Cdim * 2;
    bf16* ht  = (bf16*)(ws + off); off += (size_t)NB * Nsp * Cdim * 2;
    bf16* Qt  = (bf16*)(ws + off); off += (size_t)NB * Nsp * Cdim * 2;
    bf16* Kt  = (bf16*)(ws + off); off += (size_t)NB * Nsp * Cdim * 2;
    bf16* Vm  = (bf16*)(ws + off); off += (size_t)NB * Nsp * Cdim * 2;
    bf16* Ot  = (bf16*)(ws + off); off += (size_t)NB * Nsp * Cdim * 2;

    k_cvt_w<<<1024, 256, 0, stream>>>(wq, wqb);
    k_cvt_w<<<1024, 256, 0, stream>>>(wk, wkb);
    k_cvt_w<<<1024, 256, 0, stream>>>(wv, wvb);
    k_cvt_w<<<1024, 256, 0, stream>>>(wo, wob);
    k_gn_stats<<<64, 256, 0, stream>>>(x, stats);
    k_gn_apply<<<dim3(64, 2), 256, 0, stream>>>(x, stats, gamma, beta, ht);

    const long long hs = (long long)Nsp * Cdim;  // 2097152
    // Q/K: out[i][co] = sum_k ht[i][k] w[co][k] + b[co]   (M=4096, N=512, bias along n)
    k_gemm_nt<0, 0, 0><<<dim3(32, 4, 2), 256, 0, stream>>>(ht, hs, wqb, 0, bq, nullptr, 0, Qt, hs, 512);
    k_gemm_nt<0, 0, 0><<<dim3(32, 4, 2), 256, 0, stream>>>(ht, hs, wkb, 0, bk, nullptr, 0, Kt, hs, 512);
    // V: out[co][j] = sum_k wv[co][k] ht[j][k] + bv[co]   (M=512, N=4096, bias along m)
    k_gemm_nt<0, 1, 0><<<dim3(4, 32, 2), 256, 0, stream>>>(wvb, 0, ht, hs, bv, nullptr, 0, Vm, hs, 4096);

    k_flash<<<dim3(Nsp / 32, NB), 256, 0, stream>>>(Qt, Kt, Vm, Ot);

    // out[co][i] = x[co][i] + bo[co] + sum_k wo[co][k] Ot[i][k]   (fp32 out + residual)
    k_gemm_nt<1, 1, 1><<<dim3(4, 32, 2), 256, 0, stream>>>(wob, 0, Ot, hs, bo, x, hs, out, hs, 4096);
}

// Round 2
// 336.098 us; speedup vs baseline: 2.3486x; 2.3486x over previous
//
#include <hip/hip_runtime.h>
#include <hip/hip_bf16.h>

typedef __bf16 bf16x8 __attribute__((ext_vector_type(8)));
typedef _Float16 f16x8 __attribute__((ext_vector_type(8)));
typedef unsigned short u16x8 __attribute__((ext_vector_type(8)));
typedef float f32x4 __attribute__((ext_vector_type(4)));
using bf16 = __hip_bfloat16;

constexpr int Cdim = 512;   // channels
constexpr int Nsp  = 4096;  // d*h*w
constexpr int NB   = 2;     // batch
constexpr float SCALE = 0.04419417382415922f;  // 512^-0.5

// async 16B global->LDS (m97 pattern). LDS dest must be wave-uniform base + lane*16.
#define GL2LDS(gaddr, laddr)                                                              \
    __builtin_amdgcn_global_load_lds((const __attribute__((address_space(1))) void*)(gaddr), \
                                     (__attribute__((address_space(3))) void*)(laddr), 16, 0, 0)

// ---------------------------------------------------------------- weights fp32 -> bf16
__global__ __launch_bounds__(256) void k_cvt_w(const float* __restrict__ w, bf16* __restrict__ o) {
    int i = blockIdx.x * 256 + threadIdx.x;  // grid exactly covers 512*512
    o[i] = __float2bfloat16(w[i]);
}

// ---------------------------------------------------------------- groupnorm stats
__global__ __launch_bounds__(256) void k_gn_stats(const float* __restrict__ x, float* __restrict__ stats) {
    int bg = blockIdx.x;  // 0..63
    const float4* p = (const float4*)(x + (size_t)bg * (16 * 4096));
    float s = 0.f, s2 = 0.f;
    for (int i = threadIdx.x; i < 16384; i += 256) {
        float4 v = p[i];
        s  += v.x + v.y + v.z + v.w;
        s2 += v.x * v.x + v.y * v.y + v.z * v.z + v.w * v.w;
    }
    #pragma unroll
    for (int off = 32; off; off >>= 1) { s += __shfl_xor(s, off); s2 += __shfl_xor(s2, off); }
    __shared__ float rs[4], rs2[4];
    int w = threadIdx.x >> 6;
    if ((threadIdx.x & 63) == 0) { rs[w] = s; rs2[w] = s2; }
    __syncthreads();
    if (threadIdx.x == 0) {
        float S = rs[0] + rs[1] + rs[2] + rs[3];
        float S2 = rs2[0] + rs2[1] + rs2[2] + rs2[3];
        float mean = S * (1.f / 65536.f);
        float var  = S2 * (1.f / 65536.f) - mean * mean;
        stats[bg * 2]     = mean;
        stats[bg * 2 + 1] = rsqrtf(var + 1e-6f);
    }
}

// ---------------------------------------------------------------- groupnorm apply + transpose -> ht[b,n,c] bf16
__global__ __launch_bounds__(256) void k_gn_apply(const float* __restrict__ x, const float* __restrict__ stats,
                                                  const float* __restrict__ gamma, const float* __restrict__ beta,
                                                  bf16* __restrict__ ht) {
    int b = blockIdx.y;
    int n0 = blockIdx.x * 64;
    int tid = threadIdx.x;
    __shared__ float tile[64][65];
    int nn_l = tid & 63, cc0 = tid >> 6;
    int cc_w = tid & 63, nn0 = tid >> 6;
    for (int c0 = 0; c0 < Cdim; c0 += 64) {
        #pragma unroll
        for (int p = 0; p < 16; ++p) {
            int cc = p * 4 + cc0;
            tile[cc][nn_l] = x[(size_t)(b * Cdim + c0 + cc) * Nsp + n0 + nn_l];
        }
        __syncthreads();
        int c = c0 + cc_w, g = c >> 4;
        float mean = stats[(b * 32 + g) * 2];
        float rstd = stats[(b * 32 + g) * 2 + 1];
        float ga = gamma[c], be = beta[c];
        #pragma unroll
        for (int p = 0; p < 16; ++p) {
            int nn = p * 4 + nn0;
            float v = tile[cc_w][nn];
            ht[(size_t)(b * Nsp + n0 + nn) * Cdim + c] = __float2bfloat16((v - mean) * rstd * ga + be);
        }
        __syncthreads();
    }
}

// ---------------------------------------------------------------- MFMA dtype dispatch
template <int DT>
__device__ __forceinline__ f32x4 mma16(u16x8 a, u16x8 b, f32x4 c) {
    if constexpr (DT == 0)
        return __builtin_amdgcn_mfma_f32_16x16x32_bf16(__builtin_bit_cast(bf16x8, a),
                                                       __builtin_bit_cast(bf16x8, b), c, 0, 0, 0);
    else
        return __builtin_amdgcn_mfma_f32_16x16x32_f16(__builtin_bit_cast(f16x8, a),
                                                      __builtin_bit_cast(f16x8, b), c, 0, 0, 0);
}

// ---------------------------------------------------------------- NT GEMM (m97 structure)
// out[m][n] = sum_k A[m][k]*B[n][k] (+bias)(+resid). 2-byte operand dtypes.
// 128x128 tile, BK=64, 4 waves 2x2, global_load_lds width-16 staging, unpadded LDS.
// DT: 0=bf16 operands, 1=f16. OUTT: 0=bf16, 1=f16, 2=f32. BIAS: 0=none,1=row,2=col.
template <int DT, int OUTT, int BIAS, int RESID>
__global__ __launch_bounds__(256) void k_gemm_nt(
    const void* __restrict__ Av, long long As,
    const void* __restrict__ Bv, long long Bs,
    const float* __restrict__ bias,
    const float* __restrict__ resid, long long Rs,
    void* __restrict__ outv, long long Os,
    int N, int K) {
    const int bm = blockIdx.x, bn = blockIdx.y, bt = blockIdx.z;
    const unsigned short* Ab = (const unsigned short*)Av + (size_t)bt * As;
    const unsigned short* Bb = (const unsigned short*)Bv + (size_t)bt * Bs;
    const int tid = threadIdx.x, lane = tid & 63, w = tid >> 6;
    const int quad = lane >> 4, l16 = lane & 15;
    const int wm = w >> 1, wn = w & 1;
    __shared__ __align__(16) unsigned short Asub[128][64];  // UNPADDED: global_load_lds layout
    __shared__ __align__(16) unsigned short Bsub[128][64];
    f32x4 zero4 = {0.f, 0.f, 0.f, 0.f};
    f32x4 acc[4][4];
    #pragma unroll
    for (int i = 0; i < 4; ++i)
        #pragma unroll
        for (int j = 0; j < 4; ++j) acc[i][j] = zero4;
    const int row0 = bm * 128, col0 = bn * 128;
    const size_t Kb = (size_t)K * 2;  // row pitch in bytes
    for (int k0 = 0; k0 < K; k0 += 64) {
        const char* Abase = (const char*)Ab + (size_t)k0 * 2;
        const char* Bbase = (const char*)Bb + (size_t)k0 * 2;
        #pragma unroll
        for (int p = 0; p < 4; ++p) {
            int o = p * 4096 + tid * 16;         // byte offset into 16 KB LDS tile
            int r = o >> 7, ir = o & 127;        // row (128 B per row), byte-in-row
            GL2LDS(Abase + (size_t)(row0 + r) * Kb + ir, (char*)Asub + o);
            GL2LDS(Bbase + (size_t)(col0 + r) * Kb + ir, (char*)Bsub + o);
        }
        __syncthreads();
        #pragma unroll
        for (int ks = 0; ks < 2; ++ks) {
            u16x8 af[4], bfr[4];
            #pragma unroll
            for (int t = 0; t < 4; ++t) af[t] = *(const u16x8*)&Asub[wm * 64 + t * 16 + l16][ks * 32 + quad * 8];
            #pragma unroll
            for (int t = 0; t < 4; ++t) bfr[t] = *(const u16x8*)&Bsub[wn * 64 + t * 16 + l16][ks * 32 + quad * 8];
            #pragma unroll
            for (int tm = 0; tm < 4; ++tm)
                #pragma unroll
                for (int tn = 0; tn < 4; ++tn) acc[tm][tn] = mma16<DT>(af[tm], bfr[tn], acc[tm][tn]);
        }
        __syncthreads();
    }
    #pragma unroll
    for (int tm = 0; tm < 4; ++tm)
        #pragma unroll
        for (int tn = 0; tn < 4; ++tn)
            #pragma unroll
            for (int r = 0; r < 4; ++r) {
                int row = row0 + wm * 64 + tm * 16 + quad * 4 + r;
                int col = col0 + wn * 64 + tn * 16 + l16;
                float v = acc[tm][tn][r];
                if constexpr (BIAS == 1) v += bias[row];
                else if constexpr (BIAS == 2) v += bias[col];
                if constexpr (RESID) v += resid[(size_t)bt * Rs + (size_t)row * N + col];
                size_t oidx = (size_t)bt * Os + (size_t)row * N + col;
                if constexpr (OUTT == 2)      ((float*)outv)[oidx] = v;
                else if constexpr (OUTT == 1) ((_Float16*)outv)[oidx] = (_Float16)v;
                else                          ((bf16*)outv)[oidx] = __float2bfloat16(v);
            }
}

// ---------------------------------------------------------------- row softmax, in-place on S [rows x 4096] f16
// one block per row; applies SCALE to logits.
__global__ __launch_bounds__(256) void k_softmax(_Float16* __restrict__ S) {
    const int tid = threadIdx.x;
    _Float16* row = S + (size_t)blockIdx.x * 4096;
    f16x8 h0 = *(const f16x8*)(row + tid * 16);
    f16x8 h1 = *(const f16x8*)(row + tid * 16 + 8);
    float v[16];
    #pragma unroll
    for (int e = 0; e < 8; ++e) { v[e] = (float)h0[e] * SCALE; v[8 + e] = (float)h1[e] * SCALE; }
    float m = -1e30f;
    #pragma unroll
    for (int e = 0; e < 16; ++e) m = fmaxf(m, v[e]);
    #pragma unroll
    for (int off = 32; off; off >>= 1) m = fmaxf(m, __shfl_xor(m, off));
    __shared__ float red_m[4], red_s[4];
    if ((tid & 63) == 0) red_m[tid >> 6] = m;
    __syncthreads();
    m = fmaxf(fmaxf(red_m[0], red_m[1]), fmaxf(red_m[2], red_m[3]));
    float ex[16];
    float s = 0.f;
    #pragma unroll
    for (int e = 0; e < 16; ++e) { ex[e] = __expf(v[e] - m); s += ex[e]; }
    #pragma unroll
    for (int off = 32; off; off >>= 1) s += __shfl_xor(s, off);
    if ((tid & 63) == 0) red_s[tid >> 6] = s;
    __syncthreads();
    s = red_s[0] + red_s[1] + red_s[2] + red_s[3];
    float rinv = 1.f / s;
    f16x8 p0, p1;
    #pragma unroll
    for (int e = 0; e < 8; ++e) { p0[e] = (_Float16)(ex[e] * rinv); p1[e] = (_Float16)(ex[8 + e] * rinv); }
    *(f16x8*)(row + tid * 16) = p0;
    *(f16x8*)(row + tid * 16 + 8) = p1;
}

// ---------------------------------------------------------------- launcher
extern "C" void kernel_launch(void* const* d_in, const int* in_sizes, int n_in,
                              void* d_out, int out_size, void* d_ws, size_t ws_size,
                              hipStream_t stream) {
    const float* x     = (const float*)d_in[0];
    const float* gamma = (const float*)d_in[1];
    const float* beta  = (const float*)d_in[2];
    const float* wq = (const float*)d_in[3];  const float* bq = (const float*)d_in[4];
    const float* wk = (const float*)d_in[5];  const float* bk = (const float*)d_in[6];
    const float* wv = (const float*)d_in[7];  const float* bv = (const float*)d_in[8];
    const float* wo = (const float*)d_in[9];  const float* bo = (const float*)d_in[10];
    float* out = (float*)d_out;

    char* ws = (char*)d_ws;
    float* stats = (float*)ws;
    size_t off = 1024;
    bf16* wqb = (bf16*)(ws + off); off += (size_t)Cdim * Cdim * 2;
    bf16* wkb = (bf16*)(ws + off); off += (size_t)Cdim * Cdim * 2;
    bf16* wvb = (bf16*)(ws + off); off += (size_t)Cdim * Cdim * 2;
    bf16* wob = (bf16*)(ws + off); off += (size_t)Cdim * Cdim * 2;
    bf16* ht      = (bf16*)(ws + off);     off += (size_t)NB * Nsp * Cdim * 2;
    bf16* Qt      = (bf16*)(ws + off);     off += (size_t)NB * Nsp * Cdim * 2;
    bf16* Kt      = (bf16*)(ws + off);     off += (size_t)NB * Nsp * Cdim * 2;
    _Float16* Vm  = (_Float16*)(ws + off); off += (size_t)NB * Nsp * Cdim * 2;
    bf16* Ot      = (bf16*)(ws + off);     off += (size_t)NB * Nsp * Cdim * 2;
    _Float16* Sm  = (_Float16*)(ws + off); off += (size_t)NB * Nsp * Nsp * 2;  // 64 MB

    k_cvt_w<<<1024, 256, 0, stream>>>(wq, wqb);
    k_cvt_w<<<1024, 256, 0, stream>>>(wk, wkb);
    k_cvt_w<<<1024, 256, 0, stream>>>(wv, wvb);
    k_cvt_w<<<1024, 256, 0, stream>>>(wo, wob);
    k_gn_stats<<<64, 256, 0, stream>>>(x, stats);
    k_gn_apply<<<dim3(64, 2), 256, 0, stream>>>(x, stats, gamma, beta, ht);

    const long long hs = (long long)Nsp * Cdim;   // 2097152
    const long long ss = (long long)Nsp * Nsp;    // 16777216

    // Q/K: out[i][co] = sum_k ht[i][k] w[co][k] + b[co]   (M=4096, N=512, col bias)
    k_gemm_nt<0, 0, 2, 0><<<dim3(32, 4, 2), 256, 0, stream>>>(ht, hs, wqb, 0, bq, nullptr, 0, Qt, hs, 512, 512);
    k_gemm_nt<0, 0, 2, 0><<<dim3(32, 4, 2), 256, 0, stream>>>(ht, hs, wkb, 0, bk, nullptr, 0, Kt, hs, 512, 512);
    // V: out[co][j] = sum_k wv[co][k] ht[j][k] + bv[co]   (M=512, N=4096, row bias, f16 out)
    k_gemm_nt<0, 1, 1, 0><<<dim3(4, 32, 2), 256, 0, stream>>>(wvb, 0, ht, hs, bv, nullptr, 0, Vm, hs, 4096, 512);
    // S = Q K^T: out[i][j] (M=N=4096, K=512, no bias, f16 out; scale folded into softmax)
    k_gemm_nt<0, 1, 0, 0><<<dim3(32, 32, 2), 256, 0, stream>>>(Qt, hs, Kt, hs, nullptr, nullptr, 0, Sm, ss, 4096, 512);
    // softmax rows (8192 rows)
    k_softmax<<<NB * Nsp, 256, 0, stream>>>(Sm);
    // O = P V^T: out[i][c] = sum_j P[i][j] Vm[c][j]  (M=4096, N=512, K=4096, f16 MFMA, bf16 out)
    k_gemm_nt<1, 0, 0, 0><<<dim3(32, 4, 2), 256, 0, stream>>>(Sm, ss, Vm, hs, nullptr, nullptr, 0, Ot, hs, 512, 4096);
    // out[co][i] = x[co][i] + bo[co] + sum_k wo[co][k] Ot[i][k]   (fp32 out + residual)
    k_gemm_nt<0, 2, 1, 1><<<dim3(4, 32, 2), 256, 0, stream>>>(wob, 0, Ot, hs, bo, x, hs, out, hs, 4096, 512);
}

// Round 3
// 312.468 us; speedup vs baseline: 2.5262x; 1.0756x over previous
//
#include <hip/hip_runtime.h>
#include <hip/hip_bf16.h>

typedef __bf16 bf16x8 __attribute__((ext_vector_type(8)));
typedef _Float16 f16x8 __attribute__((ext_vector_type(8)));
typedef unsigned short u16x8 __attribute__((ext_vector_type(8)));
typedef float f32x4 __attribute__((ext_vector_type(4)));
using bf16 = __hip_bfloat16;

constexpr int Cdim = 512;   // channels
constexpr int Nsp  = 4096;  // d*h*w
constexpr int NB   = 2;     // batch
constexpr float SCALE = 0.04419417382415922f;  // 512^-0.5

// async 16B global->LDS (m97 pattern). LDS dest must be wave-uniform base + lane*16.
#define GL2LDS(gaddr, laddr)                                                              \
    __builtin_amdgcn_global_load_lds((const __attribute__((address_space(1))) void*)(gaddr), \
                                     (__attribute__((address_space(3))) void*)(laddr), 16, 0, 0)

// ---------------------------------------------------------------- all 4 weights fp32 -> bf16, one launch
__global__ __launch_bounds__(256) void k_cvt_all(const float* __restrict__ wq, const float* __restrict__ wk,
                                                 const float* __restrict__ wv, const float* __restrict__ wo,
                                                 bf16* __restrict__ wqkb, bf16* __restrict__ wvb,
                                                 bf16* __restrict__ wob) {
    int i = blockIdx.x * 256 + threadIdx.x;  // 65536 float4 groups per weight
    float4 q = ((const float4*)wq)[i];
    float4 k = ((const float4*)wk)[i];
    float4 v = ((const float4*)wv)[i];
    float4 o = ((const float4*)wo)[i];
    bf16* dq = wqkb + (size_t)i * 4;
    dq[0] = __float2bfloat16(q.x); dq[1] = __float2bfloat16(q.y);
    dq[2] = __float2bfloat16(q.z); dq[3] = __float2bfloat16(q.w);
    bf16* dk = wqkb + 262144 + (size_t)i * 4;
    dk[0] = __float2bfloat16(k.x); dk[1] = __float2bfloat16(k.y);
    dk[2] = __float2bfloat16(k.z); dk[3] = __float2bfloat16(k.w);
    bf16* dv = wvb + (size_t)i * 4;
    dv[0] = __float2bfloat16(v.x); dv[1] = __float2bfloat16(v.y);
    dv[2] = __float2bfloat16(v.z); dv[3] = __float2bfloat16(v.w);
    bf16* dw = wob + (size_t)i * 4;
    dw[0] = __float2bfloat16(o.x); dw[1] = __float2bfloat16(o.y);
    dw[2] = __float2bfloat16(o.z); dw[3] = __float2bfloat16(o.w);
}

// ---------------------------------------------------------------- groupnorm stats
__global__ __launch_bounds__(256) void k_gn_stats(const float* __restrict__ x, float* __restrict__ stats) {
    int bg = blockIdx.x;  // 0..63
    const float4* p = (const float4*)(x + (size_t)bg * (16 * 4096));
    float s = 0.f, s2 = 0.f;
    for (int i = threadIdx.x; i < 16384; i += 256) {
        float4 v = p[i];
        s  += v.x + v.y + v.z + v.w;
        s2 += v.x * v.x + v.y * v.y + v.z * v.z + v.w * v.w;
    }
    #pragma unroll
    for (int off = 32; off; off >>= 1) { s += __shfl_xor(s, off); s2 += __shfl_xor(s2, off); }
    __shared__ float rs[4], rs2[4];
    int w = threadIdx.x >> 6;
    if ((threadIdx.x & 63) == 0) { rs[w] = s; rs2[w] = s2; }
    __syncthreads();
    if (threadIdx.x == 0) {
        float S = rs[0] + rs[1] + rs[2] + rs[3];
        float S2 = rs2[0] + rs2[1] + rs2[2] + rs2[3];
        float mean = S * (1.f / 65536.f);
        float var  = S2 * (1.f / 65536.f) - mean * mean;
        stats[bg * 2]     = mean;
        stats[bg * 2 + 1] = rsqrtf(var + 1e-6f);
    }
}

// ---------------------------------------------------------------- groupnorm apply + transpose -> ht[b,n,c] bf16
__global__ __launch_bounds__(256) void k_gn_apply(const float* __restrict__ x, const float* __restrict__ stats,
                                                  const float* __restrict__ gamma, const float* __restrict__ beta,
                                                  bf16* __restrict__ ht) {
    int b = blockIdx.y;
    int n0 = blockIdx.x * 64;
    int tid = threadIdx.x;
    __shared__ float tile[64][65];
    int nn_l = tid & 63, cc0 = tid >> 6;
    int cc_w = tid & 63, nn0 = tid >> 6;
    for (int c0 = 0; c0 < Cdim; c0 += 64) {
        #pragma unroll
        for (int p = 0; p < 16; ++p) {
            int cc = p * 4 + cc0;
            tile[cc][nn_l] = x[(size_t)(b * Cdim + c0 + cc) * Nsp + n0 + nn_l];
        }
        __syncthreads();
        int c = c0 + cc_w, g = c >> 4;
        float mean = stats[(b * 32 + g) * 2];
        float rstd = stats[(b * 32 + g) * 2 + 1];
        float ga = gamma[c], be = beta[c];
        #pragma unroll
        for (int p = 0; p < 16; ++p) {
            int nn = p * 4 + nn0;
            float v = tile[cc_w][nn];
            ht[(size_t)(b * Nsp + n0 + nn) * Cdim + c] = __float2bfloat16((v - mean) * rstd * ga + be);
        }
        __syncthreads();
    }
}

// ---------------------------------------------------------------- MFMA dtype dispatch
template <int DT>
__device__ __forceinline__ f32x4 mma16(u16x8 a, u16x8 b, f32x4 c) {
    if constexpr (DT == 0)
        return __builtin_amdgcn_mfma_f32_16x16x32_bf16(__builtin_bit_cast(bf16x8, a),
                                                       __builtin_bit_cast(bf16x8, b), c, 0, 0, 0);
    else
        return __builtin_amdgcn_mfma_f32_16x16x32_f16(__builtin_bit_cast(f16x8, a),
                                                      __builtin_bit_cast(f16x8, b), c, 0, 0, 0);
}

// ---------------------------------------------------------------- NT GEMM (m97 structure) + split-K
// out[m][n] = sum_k A[m][k]*B[n][k] (+bias)(+resid). 2-byte operand dtypes, pitches lda/ldb.
// 128x128 tile, BK=64, 4 waves 2x2, global_load_lds width-16 staging, unpadded LDS.
// DT: 0=bf16, 1=f16. OUTT: 0=bf16, 1=f16, 2=f32. BIAS: 0=none,1=row,2=col,3=two-ptr col over 2*512.
// SPLITK>1: blockIdx.z = ksl*NB + bt, K-chunk = K/SPLITK, out slab z*Os (partials; BIAS/RESID must be 0).
template <int DT, int OUTT, int BIAS, int RESID, int SPLITK>
__global__ __launch_bounds__(256) void k_gemm_nt(
    const void* __restrict__ Av, long long As, int lda,
    const void* __restrict__ Bv, long long Bs, int ldb,
    const float* __restrict__ bias, const float* __restrict__ bias2,
    const float* __restrict__ resid, long long Rs,
    void* __restrict__ outv, long long Os,
    int N, int K) {
    const int bm = blockIdx.x, bn = blockIdx.y, zz = blockIdx.z;
    const int bt  = (SPLITK > 1) ? (zz % NB) : zz;
    const int ksl = (SPLITK > 1) ? (zz / NB) : 0;
    const int Kc = K / SPLITK;
    const int kbeg = ksl * Kc;
    const unsigned short* Ab = (const unsigned short*)Av + (size_t)bt * As;
    const unsigned short* Bb = (const unsigned short*)Bv + (size_t)bt * Bs;
    const int tid = threadIdx.x, lane = tid & 63, w = tid >> 6;
    const int quad = lane >> 4, l16 = lane & 15;
    const int wm = w >> 1, wn = w & 1;
    __shared__ __align__(16) unsigned short Asub[128][64];  // UNPADDED: global_load_lds layout
    __shared__ __align__(16) unsigned short Bsub[128][64];
    f32x4 zero4 = {0.f, 0.f, 0.f, 0.f};
    f32x4 acc[4][4];
    #pragma unroll
    for (int i = 0; i < 4; ++i)
        #pragma unroll
        for (int j = 0; j < 4; ++j) acc[i][j] = zero4;
    const int row0 = bm * 128, col0 = bn * 128;
    const size_t ldab = (size_t)lda * 2, ldbb = (size_t)ldb * 2;
    for (int k0 = kbeg; k0 < kbeg + Kc; k0 += 64) {
        const char* Abase = (const char*)Ab + (size_t)k0 * 2;
        const char* Bbase = (const char*)Bb + (size_t)k0 * 2;
        #pragma unroll
        for (int p = 0; p < 4; ++p) {
            int o = p * 4096 + tid * 16;         // byte offset into 16 KB LDS tile
            int r = o >> 7, ir = o & 127;        // row (128 B per row), byte-in-row
            GL2LDS(Abase + (size_t)(row0 + r) * ldab + ir, (char*)Asub + o);
            GL2LDS(Bbase + (size_t)(col0 + r) * ldbb + ir, (char*)Bsub + o);
        }
        __syncthreads();
        #pragma unroll
        for (int ks = 0; ks < 2; ++ks) {
            u16x8 af[4], bfr[4];
            #pragma unroll
            for (int t = 0; t < 4; ++t) af[t] = *(const u16x8*)&Asub[wm * 64 + t * 16 + l16][ks * 32 + quad * 8];
            #pragma unroll
            for (int t = 0; t < 4; ++t) bfr[t] = *(const u16x8*)&Bsub[wn * 64 + t * 16 + l16][ks * 32 + quad * 8];
            #pragma unroll
            for (int tm = 0; tm < 4; ++tm)
                #pragma unroll
                for (int tn = 0; tn < 4; ++tn) acc[tm][tn] = mma16<DT>(af[tm], bfr[tn], acc[tm][tn]);
        }
        __syncthreads();
    }
    #pragma unroll
    for (int tm = 0; tm < 4; ++tm)
        #pragma unroll
        for (int tn = 0; tn < 4; ++tn)
            #pragma unroll
            for (int r = 0; r < 4; ++r) {
                int row = row0 + wm * 64 + tm * 16 + quad * 4 + r;
                int col = col0 + wn * 64 + tn * 16 + l16;
                float v = acc[tm][tn][r];
                if constexpr (BIAS == 1) v += bias[row];
                else if constexpr (BIAS == 2) v += bias[col];
                else if constexpr (BIAS == 3) v += (col < 512) ? bias[col] : bias2[col - 512];
                if constexpr (RESID) v += resid[(size_t)bt * Rs + (size_t)row * N + col];
                size_t oidx = (size_t)zz * Os + (size_t)row * N + col;
                if constexpr (OUTT == 2)      ((float*)outv)[oidx] = v;
                else if constexpr (OUTT == 1) ((_Float16*)outv)[oidx] = (_Float16)v;
                else                          ((bf16*)outv)[oidx] = __float2bfloat16(v);
            }
}

// ---------------------------------------------------------------- sum 4 f16 split-K partials -> bf16
__global__ __launch_bounds__(256) void k_reduce4(const _Float16* __restrict__ P, bf16* __restrict__ O) {
    constexpr size_t SL = (size_t)NB * Nsp * Cdim;  // 4194304 elems per split slab
    size_t i = ((size_t)blockIdx.x * 256 + threadIdx.x) * 8;
    f16x8 a = *(const f16x8*)(P + i);
    f16x8 b = *(const f16x8*)(P + SL + i);
    f16x8 c = *(const f16x8*)(P + 2 * SL + i);
    f16x8 d = *(const f16x8*)(P + 3 * SL + i);
    union { bf16 h[8]; uint4 u; } r;
    #pragma unroll
    for (int e = 0; e < 8; ++e)
        r.h[e] = __float2bfloat16((float)a[e] + (float)b[e] + (float)c[e] + (float)d[e]);
    *(uint4*)(O + i) = r.u;
}

// ---------------------------------------------------------------- row softmax, in-place on S [rows x 4096] f16
__global__ __launch_bounds__(256) void k_softmax(_Float16* __restrict__ S) {
    const int tid = threadIdx.x;
    _Float16* row = S + (size_t)blockIdx.x * 4096;
    f16x8 h0 = *(const f16x8*)(row + tid * 16);
    f16x8 h1 = *(const f16x8*)(row + tid * 16 + 8);
    float v[16];
    #pragma unroll
    for (int e = 0; e < 8; ++e) { v[e] = (float)h0[e] * SCALE; v[8 + e] = (float)h1[e] * SCALE; }
    float m = -1e30f;
    #pragma unroll
    for (int e = 0; e < 16; ++e) m = fmaxf(m, v[e]);
    #pragma unroll
    for (int off = 32; off; off >>= 1) m = fmaxf(m, __shfl_xor(m, off));
    __shared__ float red_m[4], red_s[4];
    if ((tid & 63) == 0) red_m[tid >> 6] = m;
    __syncthreads();
    m = fmaxf(fmaxf(red_m[0], red_m[1]), fmaxf(red_m[2], red_m[3]));
    float ex[16];
    float s = 0.f;
    #pragma unroll
    for (int e = 0; e < 16; ++e) { ex[e] = __expf(v[e] - m); s += ex[e]; }
    #pragma unroll
    for (int off = 32; off; off >>= 1) s += __shfl_xor(s, off);
    if ((tid & 63) == 0) red_s[tid >> 6] = s;
    __syncthreads();
    s = red_s[0] + red_s[1] + red_s[2] + red_s[3];
    float rinv = 1.f / s;
    f16x8 p0, p1;
    #pragma unroll
    for (int e = 0; e < 8; ++e) { p0[e] = (_Float16)(ex[e] * rinv); p1[e] = (_Float16)(ex[8 + e] * rinv); }
    *(f16x8*)(row + tid * 16) = p0;
    *(f16x8*)(row + tid * 16 + 8) = p1;
}

// ---------------------------------------------------------------- launcher
extern "C" void kernel_launch(void* const* d_in, const int* in_sizes, int n_in,
                              void* d_out, int out_size, void* d_ws, size_t ws_size,
                              hipStream_t stream) {
    const float* x     = (const float*)d_in[0];
    const float* gamma = (const float*)d_in[1];
    const float* beta  = (const float*)d_in[2];
    const float* wq = (const float*)d_in[3];  const float* bq = (const float*)d_in[4];
    const float* wk = (const float*)d_in[5];  const float* bk = (const float*)d_in[6];
    const float* wv = (const float*)d_in[7];  const float* bv = (const float*)d_in[8];
    const float* wo = (const float*)d_in[9];  const float* bo = (const float*)d_in[10];
    float* out = (float*)d_out;

    // workspace layout (Opart aliases ht+QKt+pad, all dead by PV time)
    char* ws = (char*)d_ws;
    float* stats = (float*)ws;
    size_t off = 1024;
    bf16* wqkb = (bf16*)(ws + off); off += (size_t)1024 * 512 * 2;        // 1 MB  [1024][512] Q then K
    bf16* wvb  = (bf16*)(ws + off); off += (size_t)512 * 512 * 2;         // 0.5 MB
    bf16* wob  = (bf16*)(ws + off); off += (size_t)512 * 512 * 2;         // 0.5 MB
    _Float16* Vm = (_Float16*)(ws + off); off += (size_t)NB * Nsp * Cdim * 2;  // 8 MB  [b][c][j]
    bf16* Ot     = (bf16*)(ws + off);     off += (size_t)NB * Nsp * Cdim * 2;  // 8 MB  [b][i][c]
    _Float16* Sm = (_Float16*)(ws + off); off += (size_t)NB * Nsp * Nsp * 2;   // 64 MB [b][i][j]
    bf16* ht     = (bf16*)(ws + off);     off += (size_t)NB * Nsp * Cdim * 2;  // 8 MB  [b][n][c]
    bf16* QKt    = (bf16*)(ws + off);     off += (size_t)NB * Nsp * 1024 * 2;  // 16 MB [b][n][1024]
    off += (size_t)8 << 20;                                                    // 8 MB pad for Opart
    _Float16* Opart = (_Float16*)ht;  // 32 MB: 4 slabs x [b][i][c], aliases ht+QKt+pad

    k_cvt_all<<<256, 256, 0, stream>>>(wq, wk, wv, wo, wqkb, wvb, wob);
    k_gn_stats<<<64, 256, 0, stream>>>(x, stats);
    k_gn_apply<<<dim3(64, 2), 256, 0, stream>>>(x, stats, gamma, beta, ht);

    const long long hs = (long long)Nsp * Cdim;    // 2097152
    const long long qs = (long long)Nsp * 1024;    // 4194304
    const long long ss = (long long)Nsp * Nsp;     // 16777216

    // fused Q+K proj: QKt[i][co'] = sum_k ht[i][k] wqk[co'][k] + b  (M=4096, N=1024, 512 blocks)
    k_gemm_nt<0, 0, 3, 0, 1><<<dim3(32, 8, 2), 256, 0, stream>>>(
        ht, hs, 512, wqkb, 0, 512, bq, bk, nullptr, 0, QKt, qs, 1024, 512);
    // V: Vm[co][j] = sum_k wv[co][k] ht[j][k] + bv  (M=512, N=4096, f16 out)
    k_gemm_nt<0, 1, 1, 0, 1><<<dim3(4, 32, 2), 256, 0, stream>>>(
        wvb, 0, 512, ht, hs, 512, bv, nullptr, nullptr, 0, Vm, hs, 4096, 512);
    // S = Q K^T (M=N=4096, K=512, f16 out; scale folded into softmax)
    k_gemm_nt<0, 1, 0, 0, 1><<<dim3(32, 32, 2), 256, 0, stream>>>(
        QKt, qs, 1024, QKt + 512, qs, 1024, nullptr, nullptr, nullptr, 0, Sm, ss, 4096, 512);
    // softmax rows (8192 rows)
    k_softmax<<<NB * Nsp, 256, 0, stream>>>(Sm);
    // O = P V^T split-K=4: partials[ksl*2+bt][i][c]  (M=4096, N=512, K=4096, f16 MFMA+partials)
    k_gemm_nt<1, 1, 0, 0, 4><<<dim3(32, 4, 8), 256, 0, stream>>>(
        Sm, ss, 4096, Vm, hs, 4096, nullptr, nullptr, nullptr, 0, Opart, hs, 512, 4096);
    // reduce 4 partials -> Ot bf16
    k_reduce4<<<2048, 256, 0, stream>>>(Opart, Ot);
    // out[co][i] = x[co][i] + bo[co] + sum_k wo[co][k] Ot[i][k]  (fp32 out + residual)
    k_gemm_nt<0, 2, 1, 1, 1><<<dim3(4, 32, 2), 256, 0, stream>>>(
        wob, 0, 512, Ot, hs, 512, bo, nullptr, x, hs, out, hs, 4096, 512);
}